// Round 5
// baseline (435.479 us; speedup 1.0000x reference)
//
#include <hip/hip_runtime.h>
#include <math.h>

#define B_ 4
#define L_ 2048
#define DM 1024
#define H_ 16
#define HD_ 64
#define NH_ 64            // B_*H_
#define EPS_ 1e-6f
#define NT 48             // K' tiles: 16 k-chunks x 3 hi/lo products

typedef float f32x4 __attribute__((ext_vector_type(4)));
typedef short short8 __attribute__((ext_vector_type(8)));

typedef __attribute__((address_space(3))) void lds_v;
typedef const __attribute__((address_space(1))) void glb_v;
#define GLOAD16(g, l) __builtin_amdgcn_global_load_lds((glb_v*)(g), (lds_v*)(l), 16, 0, 0)

#define SCHED0() __builtin_amdgcn_sched_barrier(0)
#define SBAR() do { SCHED0(); __builtin_amdgcn_s_barrier(); SCHED0(); } while (0)
#define WAITV(N) do { SCHED0(); asm volatile("s_waitcnt vmcnt(" #N ")" ::: "memory"); SCHED0(); } while (0)

__device__ __forceinline__ float sigmoidf_(float x) { return 1.0f / (1.0f + expf(-x)); }

// round-to-nearest-even f32 -> bf16 bits
__device__ __forceinline__ short f2bf(float x) {
    unsigned u = __float_as_uint(x);
    unsigned r = (u + 0x7FFFu + ((u >> 16) & 1u)) >> 16;
    return (short)r;
}
__device__ __forceinline__ float bf2f(short h) {
    return __uint_as_float(((unsigned)(unsigned short)h) << 16);
}

// ---------------------------------------------------------------------------
// Split f32 array into bf16 hi/lo (x = hi + lo to ~2^-17 relative).
// ---------------------------------------------------------------------------
__global__ __launch_bounds__(256) void split_kernel(
    const float* __restrict__ in, short* __restrict__ hi, short* __restrict__ lo, int n4)
{
    const int i = blockIdx.x * 256 + threadIdx.x;
    if (i >= n4) return;
    f32x4 v = *(const f32x4*)(in + (size_t)i * 4);
    short h[4], l[4];
    #pragma unroll
    for (int j = 0; j < 4; ++j) {
        h[j] = f2bf(v[j]);
        l[j] = f2bf(v[j] - bf2f(h[j]));
    }
    typedef short short4_ __attribute__((ext_vector_type(4)));
    *(short4_*)(hi + (size_t)i * 4) = short4_{h[0], h[1], h[2], h[3]};
    *(short4_*)(lo + (size_t)i * 4) = short4_{l[0], l[1], l[2], l[3]};
}

// ---------------------------------------------------------------------------
// Deep-pipelined split-bf16 MFMA GEMM core.
//   C[BM x 256] tile of A[M,1024] @ W[N,1024]^T, hi/lo 3-product expressed as
//   K' = 3*1024: tile t=(c,p): A-src = p<2 ? Ah : Al ; B-src = p==1 ? Bl : Bh.
//   BM = MFR*32 (MFR = per-wave m-frags). 8 waves (2M x 4N).
//   K-tile BK=64 = 2 ks-quarters of 32. LDS double-buffered; per buffer:
//   [A ks0 | A ks1 | B ks0 | B ks1]. Counted vmcnt (8 for MFR=8, 6 for MFR=4),
//   prefetch distance 3 quarter-stages; drain only in last 3 tiles.
//   Invariant (verified by simulation): entering phase(t,0) the outstanding
//   quarters are {S(t,1), S(t+1,0)}; each phase issues one quarter and
//   WAITV(N) retires exactly the quarter the next phase reads, before SBAR.
//   Swizzle (both-sides): 16B slot' = slot ^ ((row>>1)&3) within 64B rows ->
//   2 lanes/bank on ds_read_b128 (free). global_load_lds writes linearly; the
//   SOURCE k-offset is inverse-swizzled to compensate.
// ---------------------------------------------------------------------------
template<int MFR>
__device__ __forceinline__ void gemm_acc(
    const short* __restrict__ Ah, const short* __restrict__ Al,
    const short* __restrict__ Bh, const short* __restrict__ Bl,
    const int row0, const int col0, char* lds, f32x4 (&acc)[MFR][4])
{
    constexpr int ABYTES = MFR * 2048;        // bytes of one A ks-quarter
    constexpr int BUFSZ  = 2 * ABYTES + 32768;
    const int tid = threadIdx.x;
    const int fr = tid & 15;
    const int kc = (tid >> 4) & 3;
    const int wr = tid >> 8;          // 0..1
    const int wc = (tid >> 6) & 3;    // 0..3
    const int rowA = wr * (MFR * 16) + fr;
    const int rowB = wc * 64 + fr;
    const int swz = ((kc ^ ((fr >> 1) & 3)) << 4);          // read swizzle (bytes)
    const int ss  = (((tid & 3) ^ ((tid >> 3) & 3)) << 3);  // src slot (elems)

    auto STAGE = [&](int tt, int ks) {
        const int b = tt & 1;
        const int c3 = tt / 3;
        const int p = tt - c3 * 3;
        const short* sA = (p < 2) ? Ah : Al;
        const short* sB = (p == 1) ? Bl : Bh;
        const int kb = c3 * 64 + ks * 32 + ss;
        char* dA = lds + b * BUFSZ + ks * ABYTES;
        char* dB = lds + b * BUFSZ + 2 * ABYTES + ks * 16384;
        #pragma unroll
        for (int j = 0; j < MFR / 4; ++j) {
            const int lb = j * 8192 + tid * 16;
            GLOAD16(sA + (size_t)(row0 + (lb >> 6)) * DM + kb, dA + lb);
        }
        #pragma unroll
        for (int j = 0; j < 2; ++j) {
            const int lb = j * 8192 + tid * 16;
            GLOAD16(sB + (size_t)(col0 + (lb >> 6)) * DM + kb, dB + lb);
        }
    };

    #pragma unroll
    for (int m = 0; m < MFR; ++m)
        #pragma unroll
        for (int n = 0; n < 4; ++n) acc[m][n] = f32x4{0.f, 0.f, 0.f, 0.f};

    // prologue: quarters in steady-state order
    STAGE(0, 0); STAGE(0, 1); STAGE(1, 0);
    if constexpr (MFR == 8) WAITV(8); else WAITV(6);
    SBAR();

    for (int t = 0; t < NT; ++t) {
        const int b = t & 1;
        #pragma unroll
        for (int ks = 0; ks < 2; ++ks) {
            const char* qA = lds + b * BUFSZ + ks * ABYTES;
            const char* qB = lds + b * BUFSZ + 2 * ABYTES + ks * 16384;
            short8 aF[MFR];
            short8 bF[4];
            #pragma unroll
            for (int m = 0; m < MFR; ++m)
                aF[m] = *(const short8*)(qA + (rowA + m * 16) * 64 + swz);
            #pragma unroll
            for (int n = 0; n < 4; ++n)
                bF[n] = *(const short8*)(qB + (rowB + n * 16) * 64 + swz);
            if (ks == 0) { if (t + 1 < NT) STAGE(t + 1, 1); }
            else         { if (t + 2 < NT) STAGE(t + 2, 0); }
            if (t < NT - 3) {
                if constexpr (MFR == 8) WAITV(8); else WAITV(6);
            } else {
                WAITV(0);
            }
            SBAR();
            __builtin_amdgcn_s_setprio(1);
            #pragma unroll
            for (int m = 0; m < MFR; ++m)
                #pragma unroll
                for (int n = 0; n < 4; ++n)
                    acc[m][n] = __builtin_amdgcn_mfma_f32_16x16x32_bf16(aF[m], bF[n], acc[m][n], 0, 0, 0);
            __builtin_amdgcn_s_setprio(0);
            SBAR();
        }
    }
}

// QKV: one packed GEMM [8192,1024]x[3072,1024]^T. BM=256 -> grid 32x12 = 384.
// Epilogue: +bias, sigmoid for q,k, scatter to [B,H,L,HD] f32.
__global__ __launch_bounds__(512, 2) void gemm_qkv_kernel(
    const short* __restrict__ xh, const short* __restrict__ xl,
    const short* __restrict__ wh, const short* __restrict__ wl,   // [3][DM][DM] packed
    const float* __restrict__ bq, const float* __restrict__ bk, const float* __restrict__ bv,
    float* __restrict__ qb, float* __restrict__ kb, float* __restrict__ vb)
{
    __shared__ char lds[131072];
    const int wg = ((int)blockIdx.x & 7) * 48 + ((int)blockIdx.x >> 3);  // XCD swizzle
    const int by = wg & 31;          // row-block (32)
    const int bx = wg >> 5;          // col-block (12), col-major chunks
    const int row0 = by * 256;
    const int col0 = bx * 256;       // global col in [0,3072)
    const int z = bx >> 2;           // 0:q 1:k 2:v (uniform per block)

    f32x4 acc[8][4];
    gemm_acc<8>(xh, xl, wh, wl, row0, col0, lds, acc);

    const int tid = threadIdx.x;
    const int fr = tid & 15, kc = (tid >> 4) & 3, wr = tid >> 8, wc = (tid >> 6) & 3;
    const float* __restrict__ bias = (z == 0) ? bq : (z == 1) ? bk : bv;
    float* __restrict__ outp       = (z == 0) ? qb : (z == 1) ? kb : vb;
    #pragma unroll
    for (int m = 0; m < 8; ++m) {
        const int gr0 = row0 + wr * 128 + m * 16 + kc * 4;
        #pragma unroll
        for (int n = 0; n < 4; ++n) {
            const int jj = col0 + wc * 64 + n * 16 + fr;
            const int j = jj & 1023;
            const float bj = bias[j];
            const int h = j >> 6, dd = j & 63;
            #pragma unroll
            for (int r2 = 0; r2 < 4; ++r2) {
                const int i = gr0 + r2;
                const int nn = i >> 11, l = i & (L_ - 1);
                float v = acc[m][n][r2] + bj;
                if (z < 2) v = sigmoidf_(v);
                outp[(((size_t)(nn * H_ + h)) * L_ + l) * HD_ + dd] = v;
            }
        }
    }
}

// Final GEMM: out = attn_hi/lo @ Wo^T + bo. BM=128 -> grid 64x4 = 256.
__global__ __launch_bounds__(512, 2) void gemm_out_kernel(
    const short* __restrict__ ah, const short* __restrict__ al,
    const short* __restrict__ wh, const short* __restrict__ wl,
    const float* __restrict__ bias, float* __restrict__ outp)
{
    __shared__ char lds[98304];
    const int wg = ((int)blockIdx.x & 7) * 32 + ((int)blockIdx.x >> 3);
    const int by = wg & 63;
    const int bx = wg >> 6;          // 0..3
    const int row0 = by * 128;
    const int col0 = bx * 256;

    f32x4 acc[4][4];
    gemm_acc<4>(ah, al, wh, wl, row0, col0, lds, acc);

    const int tid = threadIdx.x;
    const int fr = tid & 15, kc = (tid >> 4) & 3, wr = tid >> 8, wc = (tid >> 6) & 3;
    #pragma unroll
    for (int m = 0; m < 4; ++m) {
        const int gr0 = row0 + wr * 64 + m * 16 + kc * 4;
        #pragma unroll
        for (int n = 0; n < 4; ++n) {
            const int col = col0 + wc * 64 + n * 16 + fr;
            const float bj = bias[col];
            #pragma unroll
            for (int r2 = 0; r2 < 4; ++r2)
                outp[(size_t)(gr0 + r2) * DM + col] = acc[m][n][r2] + bj;
        }
    }
}

// ---------------------------------------------------------------------------
// colsum partials: qsum_p[nh][chunk][d] = sum over 128 l's
// ---------------------------------------------------------------------------
__global__ __launch_bounds__(256) void colsum_part_kernel(
    const float* __restrict__ q, const float* __restrict__ k,
    float* __restrict__ qsum_p, float* __restrict__ ksum_p)
{
    const int nh = blockIdx.x, ch = blockIdx.y;
    const float* qp = q + (size_t)nh * L_ * HD_;
    const float* kp = k + (size_t)nh * L_ * HD_;
    const int d = threadIdx.x & 63;
    const int c = threadIdx.x >> 6;
    float qs = 0.f, ks = 0.f;
    for (int l = ch * 128 + c; l < (ch + 1) * 128; l += 4) {
        qs += qp[(size_t)l * HD_ + d];
        ks += kp[(size_t)l * HD_ + d];
    }
    __shared__ float sq[4][64], sk[4][64];
    sq[c][d] = qs; sk[c][d] = ks;
    __syncthreads();
    if (c == 0) {
        qsum_p[(nh * 16 + ch) * 64 + d] = sq[0][d] + sq[1][d] + sq[2][d] + sq[3][d];
        ksum_p[(nh * 16 + ch) * 64 + d] = sk[0][d] + sk[1][d] + sk[2][d] + sk[3][d];
    }
}

// generic: reduce 16 chunk-partials for two arrays
__global__ __launch_bounds__(64) void reduce16_2_kernel(
    const float* __restrict__ ap, const float* __restrict__ bp,
    float* __restrict__ a, float* __restrict__ b)
{
    const int nh = blockIdx.x, d = threadIdx.x;
    float sa_ = 0.f, sb_ = 0.f;
    #pragma unroll
    for (int i = 0; i < 16; ++i) {
        sa_ += ap[(nh * 16 + i) * 64 + d];
        sb_ += bp[(nh * 16 + i) * 64 + d];
    }
    a[nh * 64 + d] = sa_;
    b[nh * 64 + d] = sb_;
}

// ---------------------------------------------------------------------------
// stage1: per l compute si (stored), so (used inline); partial qsi/kso.
// ---------------------------------------------------------------------------
__global__ __launch_bounds__(256) void stage1_part_kernel(
    const float* __restrict__ q, const float* __restrict__ k,
    const float* __restrict__ qsum, const float* __restrict__ ksum,
    float* __restrict__ si, float* __restrict__ qsi_p, float* __restrict__ kso_p)
{
    const int nh = blockIdx.x, ch = blockIdx.y;
    const float* qp = q + (size_t)nh * L_ * HD_;
    const float* kp = k + (size_t)nh * L_ * HD_;
    const int lane = threadIdx.x & 63;
    const int w = threadIdx.x >> 6;
    const float ksv = ksum[nh * 64 + lane] + EPS_;
    const float qsv = qsum[nh * 64 + lane] + EPS_;
    float qsi_acc = 0.f, kso_acc = 0.f;
    for (int l = ch * 128 + w; l < (ch + 1) * 128; l += 4) {
        const float qv = qp[(size_t)l * HD_ + lane];
        const float kv = kp[(size_t)l * HD_ + lane];
        float a = (qv + EPS_) * ksv;
        float b = (kv + EPS_) * qsv;
        #pragma unroll
        for (int off = 32; off >= 1; off >>= 1) {
            a += __shfl_xor(a, off, 64);
            b += __shfl_xor(b, off, 64);
        }
        const float siv = 1.f / a;
        const float sov = 1.f / b;
        if (lane == 0) si[nh * L_ + l] = siv;
        qsi_acc += qv * siv;
        kso_acc += kv * sov;
    }
    __shared__ float s1[4][64], s2[4][64];
    s1[w][lane] = qsi_acc; s2[w][lane] = kso_acc;
    __syncthreads();
    if (w == 0) {
        qsi_p[(nh * 16 + ch) * 64 + lane] = s1[0][lane] + s1[1][lane] + s1[2][lane] + s1[3][lane];
        kso_p[(nh * 16 + ch) * 64 + lane] = s2[0][lane] + s2[1][lane] + s2[2][lane] + s2[3][lane];
    }
}

// ---------------------------------------------------------------------------
// stage2: sa = sigmoid(conserved_sink); sc_raw = exp(clip(conserved_source));
// psum partials for softmax denominator.
// ---------------------------------------------------------------------------
__global__ __launch_bounds__(256) void stage2_part_kernel(
    const float* __restrict__ q, const float* __restrict__ k,
    const float* __restrict__ qsi, const float* __restrict__ kso,
    float* __restrict__ sa, float* __restrict__ sc, float* __restrict__ psum_p)
{
    const int nh = blockIdx.x, ch = blockIdx.y;
    const float* qp = q + (size_t)nh * L_ * HD_;
    const float* kp = k + (size_t)nh * L_ * HD_;
    const int lane = threadIdx.x & 63;
    const int w = threadIdx.x >> 6;
    const float ksov = kso[nh * 64 + lane] + EPS_;
    const float qsiv = qsi[nh * 64 + lane] + EPS_;
    float psum = 0.f;
    for (int l = ch * 128 + w; l < (ch + 1) * 128; l += 4) {
        float a = (qp[(size_t)l * HD_ + lane] + EPS_) * ksov;
        float b = (kp[(size_t)l * HD_ + lane] + EPS_) * qsiv;
        #pragma unroll
        for (int off = 32; off >= 1; off >>= 1) {
            a += __shfl_xor(a, off, 64);
            b += __shfl_xor(b, off, 64);
        }
        b = fminf(1.f, fmaxf(-1.f, b));
        const float p = expf(b);
        if (lane == 0) {
            sa[nh * L_ + l] = sigmoidf_(a);
            sc[nh * L_ + l] = p;
        }
        psum += p;    // same on all lanes of wave
    }
    __shared__ float sp[4];
    if (lane == 0) sp[w] = psum;
    __syncthreads();
    if (threadIdx.x == 0) psum_p[nh * 16 + ch] = sp[0] + sp[1] + sp[2] + sp[3];
}

// ---------------------------------------------------------------------------
// kv partial over 256-l chunk: kvp[nh][ch][d][m] = sum k[l][d]*v[l][m]*sc[l]*scale
// ---------------------------------------------------------------------------
__global__ __launch_bounds__(256) void kv_part_kernel(
    const float* __restrict__ k, const float* __restrict__ v,
    const float* __restrict__ sc, const float* __restrict__ psum_p,
    float* __restrict__ kvp)
{
    const int nh = blockIdx.x, ch = blockIdx.y;
    const float* kp = k + (size_t)nh * L_ * HD_;
    const float* vp = v + (size_t)nh * L_ * HD_;
    const float* scp = sc + (size_t)nh * L_;
    float tot = 0.f;
    #pragma unroll
    for (int i = 0; i < 16; ++i) tot += psum_p[nh * 16 + i];
    const float scale = (float)L_ / tot;

    const int m  = threadIdx.x & 63;
    const int dg = threadIdx.x >> 6;
    float acc[16] = {0.f};
    __shared__ float ks[32][64], vs[32][64];
    for (int l0 = ch * 256; l0 < (ch + 1) * 256; l0 += 32) {
        for (int i = threadIdx.x; i < 32 * 64; i += 256) {
            const int ll = i >> 6, dd = i & 63;
            ks[ll][dd] = kp[(size_t)(l0 + ll) * HD_ + dd];
            vs[ll][dd] = vp[(size_t)(l0 + ll) * HD_ + dd] * (scp[l0 + ll] * scale);
        }
        __syncthreads();
        #pragma unroll 8
        for (int ll = 0; ll < 32; ++ll) {
            const float vv = vs[ll][m];
            #pragma unroll
            for (int dd = 0; dd < 16; ++dd) acc[dd] += ks[ll][dg * 16 + dd] * vv;
        }
        __syncthreads();
    }
    #pragma unroll
    for (int dd = 0; dd < 16; ++dd)
        kvp[((size_t)(nh * 8 + ch) * 64 + (dg * 16 + dd)) * 64 + m] = acc[dd];
}

__global__ __launch_bounds__(256) void kv_reduce_kernel(
    const float* __restrict__ kvp, float* __restrict__ kvb)
{
    const int nh = blockIdx.x;
    for (int e = threadIdx.x; e < 4096; e += 256) {
        float s = 0.f;
        #pragma unroll
        for (int c = 0; c < 8; ++c) s += kvp[(size_t)(nh * 8 + c) * 4096 + e];
        kvb[(size_t)nh * 4096 + e] = s;
    }
}

// ---------------------------------------------------------------------------
// out: attn[n][l][h*64+m] = sa*si*(q[l,:]·kv[:,m]) -> bf16 hi/lo split store
// ---------------------------------------------------------------------------
__global__ __launch_bounds__(256) void out_kernel(
    const float* __restrict__ q, const float* __restrict__ kvb,
    const float* __restrict__ si, const float* __restrict__ sa,
    short* __restrict__ attn_h, short* __restrict__ attn_l)
{
    const int nh = blockIdx.x;
    const int n = nh >> 4;
    const int h = nh & 15;
    const int l0 = blockIdx.y * 64;
    __shared__ float kvs[64][64];
    __shared__ float qs[64][64];
    for (int i = threadIdx.x; i < 4096; i += 256)
        kvs[i >> 6][i & 63] = kvb[(size_t)nh * 4096 + i];
    for (int i = threadIdx.x; i < 4096; i += 256) {
        const int ll = i >> 6, dd = i & 63;
        qs[ll][dd] = q[((size_t)nh * L_ + (l0 + ll)) * HD_ + dd];
    }
    __syncthreads();
    const int m = threadIdx.x & 63;
    const int lg = threadIdx.x >> 6;
    for (int ll = lg; ll < 64; ll += 4) {
        const int l = l0 + ll;
        float acc = 0.f;
        #pragma unroll
        for (int d = 0; d < 64; ++d) acc += qs[ll][d] * kvs[d][m];
        const float val = acc * si[nh * L_ + l] * sa[nh * L_ + l];
        const size_t idx = ((size_t)n * L_ + l) * DM + h * 64 + m;
        const short hb = f2bf(val);
        attn_h[idx] = hb;
        attn_l[idx] = f2bf(val - bf2f(hb));
    }
}

extern "C" void kernel_launch(void* const* d_in, const int* in_sizes, int n_in,
                              void* d_out, int out_size, void* d_ws, size_t ws_size,
                              hipStream_t stream)
{
    const float* x  = (const float*)d_in[0];
    const float* Wq = (const float*)d_in[1];
    const float* bq = (const float*)d_in[2];
    const float* Wk = (const float*)d_in[3];
    const float* bk = (const float*)d_in[4];
    const float* Wv = (const float*)d_in[5];
    const float* bv = (const float*)d_in[6];
    const float* Wo = (const float*)d_in[7];
    const float* bo = (const float*)d_in[8];
    float* out = (float*)d_out;

    float* ws = (float*)d_ws;
    size_t off = 0;
    const size_t big = (size_t)B_ * L_ * DM;   // 8,388,608 elems
    float* qbuf = ws + off; off += big;
    float* kbuf = ws + off; off += big;
    float* vbuf = ws + off; off += big;
    // union region: x hi/lo during projections, attn hi/lo afterwards
    short* xh = (short*)(ws + off);
    short* xl = xh + big;
    short* attn_h = xh;
    short* attn_l = xl;
    off += big;
    short* wh3 = (short*)(ws + off); off += (size_t)3 * DM * DM / 2;
    short* wl3 = (short*)(ws + off); off += (size_t)3 * DM * DM / 2;
    short* woh = (short*)(ws + off); off += (size_t)DM * DM / 2;
    short* wol = (short*)(ws + off); off += (size_t)DM * DM / 2;
    float* kvp    = ws + off; off += (size_t)NH_ * 8 * 64 * 64;
    float* kvb    = ws + off; off += (size_t)NH_ * 64 * 64;
    float* qsum_p = ws + off; off += NH_ * 16 * 64;
    float* ksum_p = ws + off; off += NH_ * 16 * 64;
    float* qsi_p  = ws + off; off += NH_ * 16 * 64;
    float* kso_p  = ws + off; off += NH_ * 16 * 64;
    float* psum_p = ws + off; off += NH_ * 16;
    float* qsum   = ws + off; off += NH_ * 64;
    float* ksum   = ws + off; off += NH_ * 64;
    float* qsi    = ws + off; off += NH_ * 64;
    float* kso    = ws + off; off += NH_ * 64;
    float* si     = ws + off; off += NH_ * L_;
    float* sa     = ws + off; off += NH_ * L_;
    float* sc     = ws + off; off += NH_ * L_;

    // 1. split inputs to bf16 hi/lo
    split_kernel<<<big / 4 / 256, 256, 0, stream>>>(x, xh, xl, (int)(big / 4));
    const int wblk = DM * DM / 4 / 256;   // 1024
    split_kernel<<<wblk, 256, 0, stream>>>(Wq, wh3,               wl3,               DM * DM / 4);
    split_kernel<<<wblk, 256, 0, stream>>>(Wk, wh3 + DM * DM,     wl3 + DM * DM,     DM * DM / 4);
    split_kernel<<<wblk, 256, 0, stream>>>(Wv, wh3 + 2 * DM * DM, wl3 + 2 * DM * DM, DM * DM / 4);
    split_kernel<<<wblk, 256, 0, stream>>>(Wo, woh,               wol,               DM * DM / 4);

    // 2. QKV projection GEMM (packed N'=3072, deep-pipelined MFMA)
    gemm_qkv_kernel<<<384, 512, 0, stream>>>(xh, xl, wh3, wl3, bq, bk, bv, qbuf, kbuf, vbuf);

    // 3. flow-conservation normalizations
    dim3 g16(NH_, 16);
    colsum_part_kernel<<<g16, 256, 0, stream>>>(qbuf, kbuf, qsum_p, ksum_p);
    reduce16_2_kernel<<<NH_, 64, 0, stream>>>(qsum_p, ksum_p, qsum, ksum);
    stage1_part_kernel<<<g16, 256, 0, stream>>>(qbuf, kbuf, qsum, ksum, si, qsi_p, kso_p);
    reduce16_2_kernel<<<NH_, 64, 0, stream>>>(qsi_p, kso_p, qsi, kso);
    stage2_part_kernel<<<g16, 256, 0, stream>>>(qbuf, kbuf, qsi, kso, sa, sc, psum_p);

    // 4. linear-attention kv + out
    kv_part_kernel<<<dim3(NH_, 8), 256, 0, stream>>>(kbuf, vbuf, sc, psum_p, kvp);
    kv_reduce_kernel<<<NH_, 256, 0, stream>>>(kvp, kvb);
    out_kernel<<<dim3(NH_, L_ / 64), 256, 0, stream>>>(qbuf, kvb, si, sa, attn_h, attn_l);

    // 5. output projection GEMM
    gemm_out_kernel<<<256, 512, 0, stream>>>(attn_h, attn_l, woh, wol, bo, out);
}

// Round 6
// 418.470 us; speedup vs baseline: 1.0406x; 1.0406x over previous
//
#include <hip/hip_runtime.h>
#include <math.h>

#define B_ 4
#define L_ 2048
#define DM 1024
#define H_ 16
#define HD_ 64
#define NH_ 64            // B_*H_
#define EPS_ 1e-6f
#define NT 48             // K' tiles: 16 k-chunks x 3 hi/lo products

// GEMM tile geometry: BM=256, BN=128, BK=64; 8 waves (4M x 2N), per-wave 64x64.
#define BUFA 32768        // 256 rows x 128 B
#define BUFB 16384        // 128 rows x 128 B
#define BUFSZ 49152       // A + B, one K-tile
// LDS = 3 * BUFSZ = 147456 <= 160 KiB

typedef float f32x4 __attribute__((ext_vector_type(4)));
typedef short short8 __attribute__((ext_vector_type(8)));

typedef __attribute__((address_space(3))) void lds_v;
typedef const __attribute__((address_space(1))) void glb_v;
#define GLOAD16(g, l) __builtin_amdgcn_global_load_lds((glb_v*)(g), (lds_v*)(l), 16, 0, 0)

#define SCHED0() __builtin_amdgcn_sched_barrier(0)
#define SBAR() do { SCHED0(); __builtin_amdgcn_s_barrier(); SCHED0(); } while (0)
#define WAITV(N) do { SCHED0(); asm volatile("s_waitcnt vmcnt(" #N ")" ::: "memory"); SCHED0(); } while (0)

__device__ __forceinline__ float sigmoidf_(float x) { return 1.0f / (1.0f + expf(-x)); }

// round-to-nearest-even f32 -> bf16 bits
__device__ __forceinline__ short f2bf(float x) {
    unsigned u = __float_as_uint(x);
    unsigned r = (u + 0x7FFFu + ((u >> 16) & 1u)) >> 16;
    return (short)r;
}
__device__ __forceinline__ float bf2f(short h) {
    return __uint_as_float(((unsigned)(unsigned short)h) << 16);
}

// ---------------------------------------------------------------------------
// Split f32 array into bf16 hi/lo (x = hi + lo to ~2^-17 relative).
// ---------------------------------------------------------------------------
__global__ __launch_bounds__(256) void split_kernel(
    const float* __restrict__ in, short* __restrict__ hi, short* __restrict__ lo, int n4)
{
    const int i = blockIdx.x * 256 + threadIdx.x;
    if (i >= n4) return;
    f32x4 v = *(const f32x4*)(in + (size_t)i * 4);
    short h[4], l[4];
    #pragma unroll
    for (int j = 0; j < 4; ++j) {
        h[j] = f2bf(v[j]);
        l[j] = f2bf(v[j] - bf2f(h[j]));
    }
    typedef short short4_ __attribute__((ext_vector_type(4)));
    *(short4_*)(hi + (size_t)i * 4) = short4_{h[0], h[1], h[2], h[3]};
    *(short4_*)(lo + (size_t)i * 4) = short4_{l[0], l[1], l[2], l[3]};
}

// ---------------------------------------------------------------------------
// Counted-vmcnt triple-buffer split-bf16 MFMA GEMM core.
//   C[256 x 128] tile of A[M,1024] @ W[N,1024]^T; hi/lo 3-product as K'=3072:
//   tile t=(c3,p): A-src = p<2 ? Ah : Al ; B-src = p==1 ? Bl : Bh; kb=c3*64.
//   8 waves (4M x 2N), per-wave 64x64 -> acc[4][4] (64 VGPR).
//   TRIPLE-buffered LDS, 2-tile-ahead prefetch: tile t's 6 loads issued
//   during t-2.  End-of-tile wait = vmcnt(6): retires exactly tile (t+1)'s
//   loads while the 6 newest (t+2's) fly.  Drain only at the last 2 tiles.
//   ONE barrier per K-tile: buffers t%3 (read) and (t+2)%3 (write) are
//   disjoint, so no intra-tile barriers are needed -> waves slip freely.
//   Swizzle (both-sides involution on 16B slots of 128B rows):
//   slot' = slot ^ (row&7); gload_lds writes linearly with inverse-swizzled
//   global k-offset; ds_read applies the same XOR -> 2 lanes/slot (free).
// ---------------------------------------------------------------------------
__device__ __forceinline__ void gemm_acc(
    const short* __restrict__ Ah, const short* __restrict__ Al,
    const short* __restrict__ Bh, const short* __restrict__ Bl,
    const int row0, const int col0, char* lds, f32x4 (&acc)[4][4])
{
    const int tid = threadIdx.x;
    const int fr = tid & 15;          // C-col fragment index
    const int kc = (tid >> 4) & 3;    // k-chunk within kstep (8 elems each)
    const int w  = tid >> 6;
    const int wr = w >> 1;            // 0..3 (M)
    const int wc = w & 1;             // 0..1 (N)

    auto STAGE = [&](int tt) {
        const int c3 = tt / 3;
        const int p  = tt - c3 * 3;
        const short* sA = (p < 2) ? Ah : Al;
        const short* sB = (p == 1) ? Bl : Bh;
        const int kb = c3 * 64;
        char* dst = lds + (tt % 3) * BUFSZ;
        #pragma unroll
        for (int j = 0; j < 4; ++j) {
            const int lb = j * 8192 + tid * 16;
            const int row = lb >> 7;
            const int srck = ((((lb >> 4) & 7) ^ (row & 7)) << 3);
            GLOAD16(sA + (size_t)(row0 + row) * DM + kb + srck, dst + lb);
        }
        #pragma unroll
        for (int j = 0; j < 2; ++j) {
            const int lb = j * 8192 + tid * 16;
            const int row = lb >> 7;
            const int srck = ((((lb >> 4) & 7) ^ (row & 7)) << 3);
            GLOAD16(sB + (size_t)(col0 + row) * DM + kb + srck, dst + BUFA + lb);
        }
    };

    #pragma unroll
    for (int m = 0; m < 4; ++m)
        #pragma unroll
        for (int n = 0; n < 4; ++n) acc[m][n] = f32x4{0.f, 0.f, 0.f, 0.f};

    // prologue: 2 tiles in flight (12 loads); retire the oldest 6 (tile 0)
    STAGE(0); STAGE(1);
    WAITV(6);
    SBAR();

    for (int t = 0; t < NT; ++t) {
        const char* bufA = lds + (t % 3) * BUFSZ;
        const char* bufB = bufA + BUFA;
        short8 aF[4], bF[4];

        // ---- kstep 0 (k 0..31): slot s = kc ----
        #pragma unroll
        for (int m = 0; m < 4; ++m) {
            const int rA = wr * 64 + m * 16 + fr;
            aF[m] = *(const short8*)(bufA + rA * 128 + (((kc) ^ (rA & 7)) << 4));
        }
        #pragma unroll
        for (int n = 0; n < 4; ++n) {
            const int rB = wc * 64 + n * 16 + fr;
            bF[n] = *(const short8*)(bufB + rB * 128 + (((kc) ^ (rB & 7)) << 4));
        }
        if (t + 2 < NT) STAGE(t + 2);
        __builtin_amdgcn_s_setprio(1);
        #pragma unroll
        for (int m = 0; m < 4; ++m)
            #pragma unroll
            for (int n = 0; n < 4; ++n)
                acc[m][n] = __builtin_amdgcn_mfma_f32_16x16x32_bf16(aF[m], bF[n], acc[m][n], 0, 0, 0);
        __builtin_amdgcn_s_setprio(0);

        // ---- kstep 1 (k 32..63): slot s = 4 + kc ----
        #pragma unroll
        for (int m = 0; m < 4; ++m) {
            const int rA = wr * 64 + m * 16 + fr;
            aF[m] = *(const short8*)(bufA + rA * 128 + (((4 + kc) ^ (rA & 7)) << 4));
        }
        #pragma unroll
        for (int n = 0; n < 4; ++n) {
            const int rB = wc * 64 + n * 16 + fr;
            bF[n] = *(const short8*)(bufB + rB * 128 + (((4 + kc) ^ (rB & 7)) << 4));
        }
        __builtin_amdgcn_s_setprio(1);
        #pragma unroll
        for (int m = 0; m < 4; ++m)
            #pragma unroll
            for (int n = 0; n < 4; ++n)
                acc[m][n] = __builtin_amdgcn_mfma_f32_16x16x32_bf16(aF[m], bF[n], acc[m][n], 0, 0, 0);
        __builtin_amdgcn_s_setprio(0);

        // boundary: ensure tile (t+1)'s loads (issued during t-1) landed.
        if (t + 2 < NT) { WAITV(6); } else { WAITV(0); }
        SBAR();
    }
}

// QKV: packed GEMM [8192,1024] x [3072,1024]^T.  Grid 32x24 = 768 (3.0/CU).
// Epilogue: +bias, sigmoid for q,k, scatter to [B,H,L,HD] f32.
__global__ __launch_bounds__(512, 2) void gemm_qkv_kernel(
    const short* __restrict__ xh, const short* __restrict__ xl,
    const short* __restrict__ wh, const short* __restrict__ wl,   // [3][DM][DM] packed
    const float* __restrict__ bq, const float* __restrict__ bk, const float* __restrict__ bv,
    float* __restrict__ qb, float* __restrict__ kb, float* __restrict__ vb)
{
    __shared__ char lds[3 * BUFSZ];
    const int wg = ((int)blockIdx.x & 7) * 96 + ((int)blockIdx.x >> 3);  // XCD swizzle (768%8==0)
    const int by = wg & 31;          // 32 row-blocks
    const int bx = wg >> 5;          // 24 col-blocks
    const int row0 = by * 256;
    const int col0 = bx * 128;       // in [0,3072)
    const int z = bx >> 3;           // 0:q 1:k 2:v (128*8=1024 per z, uniform per block)

    f32x4 acc[4][4];
    gemm_acc(xh, xl, wh, wl, row0, col0, lds, acc);

    const int tid = threadIdx.x;
    const int fr = tid & 15, kc = (tid >> 4) & 3, wr = (tid >> 6) >> 1, wc = (tid >> 6) & 1;
    const float* __restrict__ bias = (z == 0) ? bq : (z == 1) ? bk : bv;
    float* __restrict__ outp       = (z == 0) ? qb : (z == 1) ? kb : vb;
    #pragma unroll
    for (int m = 0; m < 4; ++m) {
        const int gr0 = row0 + wr * 64 + m * 16 + kc * 4;
        #pragma unroll
        for (int n = 0; n < 4; ++n) {
            const int j = (col0 & 1023) + wc * 64 + n * 16 + fr;
            const float bj = bias[j];
            const int h = j >> 6, dd = j & 63;
            #pragma unroll
            for (int r2 = 0; r2 < 4; ++r2) {
                const int i = gr0 + r2;
                const int nn = i >> 11, l = i & (L_ - 1);
                float v = acc[m][n][r2] + bj;
                if (z < 2) v = sigmoidf_(v);
                outp[(((size_t)(nn * H_ + h)) * L_ + l) * HD_ + dd] = v;
            }
        }
    }
}

// Final GEMM: out = attn_hi/lo @ Wo^T + bo.  Grid 32x8 = 256 (1.0/CU exact).
__global__ __launch_bounds__(512, 2) void gemm_out_kernel(
    const short* __restrict__ ah, const short* __restrict__ al,
    const short* __restrict__ wh, const short* __restrict__ wl,
    const float* __restrict__ bias, float* __restrict__ outp)
{
    __shared__ char lds[3 * BUFSZ];
    const int wg = ((int)blockIdx.x & 7) * 32 + ((int)blockIdx.x >> 3);  // 256%8==0
    const int by = wg & 31;
    const int bx = wg >> 5;          // 0..7
    const int row0 = by * 256;
    const int col0 = bx * 128;

    f32x4 acc[4][4];
    gemm_acc(ah, al, wh, wl, row0, col0, lds, acc);

    const int tid = threadIdx.x;
    const int fr = tid & 15, kc = (tid >> 4) & 3, wr = (tid >> 6) >> 1, wc = (tid >> 6) & 1;
    #pragma unroll
    for (int m = 0; m < 4; ++m) {
        const int gr0 = row0 + wr * 64 + m * 16 + kc * 4;
        #pragma unroll
        for (int n = 0; n < 4; ++n) {
            const int col = col0 + wc * 64 + n * 16 + fr;
            const float bj = bias[col];
            #pragma unroll
            for (int r2 = 0; r2 < 4; ++r2)
                outp[(size_t)(gr0 + r2) * DM + col] = acc[m][n][r2] + bj;
        }
    }
}

// ---------------------------------------------------------------------------
// colsum partials: qsum_p[nh][chunk][d] = sum over 128 l's
// ---------------------------------------------------------------------------
__global__ __launch_bounds__(256) void colsum_part_kernel(
    const float* __restrict__ q, const float* __restrict__ k,
    float* __restrict__ qsum_p, float* __restrict__ ksum_p)
{
    const int nh = blockIdx.x, ch = blockIdx.y;
    const float* qp = q + (size_t)nh * L_ * HD_;
    const float* kp = k + (size_t)nh * L_ * HD_;
    const int d = threadIdx.x & 63;
    const int c = threadIdx.x >> 6;
    float qs = 0.f, ks = 0.f;
    for (int l = ch * 128 + c; l < (ch + 1) * 128; l += 4) {
        qs += qp[(size_t)l * HD_ + d];
        ks += kp[(size_t)l * HD_ + d];
    }
    __shared__ float sq[4][64], sk[4][64];
    sq[c][d] = qs; sk[c][d] = ks;
    __syncthreads();
    if (c == 0) {
        qsum_p[(nh * 16 + ch) * 64 + d] = sq[0][d] + sq[1][d] + sq[2][d] + sq[3][d];
        ksum_p[(nh * 16 + ch) * 64 + d] = sk[0][d] + sk[1][d] + sk[2][d] + sk[3][d];
    }
}

// generic: reduce 16 chunk-partials for two arrays
__global__ __launch_bounds__(64) void reduce16_2_kernel(
    const float* __restrict__ ap, const float* __restrict__ bp,
    float* __restrict__ a, float* __restrict__ b)
{
    const int nh = blockIdx.x, d = threadIdx.x;
    float sa_ = 0.f, sb_ = 0.f;
    #pragma unroll
    for (int i = 0; i < 16; ++i) {
        sa_ += ap[(nh * 16 + i) * 64 + d];
        sb_ += bp[(nh * 16 + i) * 64 + d];
    }
    a[nh * 64 + d] = sa_;
    b[nh * 64 + d] = sb_;
}

// ---------------------------------------------------------------------------
// stage1: per l compute si (stored), so (used inline); partial qsi/kso.
// ---------------------------------------------------------------------------
__global__ __launch_bounds__(256) void stage1_part_kernel(
    const float* __restrict__ q, const float* __restrict__ k,
    const float* __restrict__ qsum, const float* __restrict__ ksum,
    float* __restrict__ si, float* __restrict__ qsi_p, float* __restrict__ kso_p)
{
    const int nh = blockIdx.x, ch = blockIdx.y;
    const float* qp = q + (size_t)nh * L_ * HD_;
    const float* kp = k + (size_t)nh * L_ * HD_;
    const int lane = threadIdx.x & 63;
    const int w = threadIdx.x >> 6;
    const float ksv = ksum[nh * 64 + lane] + EPS_;
    const float qsv = qsum[nh * 64 + lane] + EPS_;
    float qsi_acc = 0.f, kso_acc = 0.f;
    for (int l = ch * 128 + w; l < (ch + 1) * 128; l += 4) {
        const float qv = qp[(size_t)l * HD_ + lane];
        const float kv = kp[(size_t)l * HD_ + lane];
        float a = (qv + EPS_) * ksv;
        float b = (kv + EPS_) * qsv;
        #pragma unroll
        for (int off = 32; off >= 1; off >>= 1) {
            a += __shfl_xor(a, off, 64);
            b += __shfl_xor(b, off, 64);
        }
        const float siv = 1.f / a;
        const float sov = 1.f / b;
        if (lane == 0) si[nh * L_ + l] = siv;
        qsi_acc += qv * siv;
        kso_acc += kv * sov;
    }
    __shared__ float s1[4][64], s2[4][64];
    s1[w][lane] = qsi_acc; s2[w][lane] = kso_acc;
    __syncthreads();
    if (w == 0) {
        qsi_p[(nh * 16 + ch) * 64 + lane] = s1[0][lane] + s1[1][lane] + s1[2][lane] + s1[3][lane];
        kso_p[(nh * 16 + ch) * 64 + lane] = s2[0][lane] + s2[1][lane] + s2[2][lane] + s2[3][lane];
    }
}

// ---------------------------------------------------------------------------
// stage2: sa = sigmoid(conserved_sink); sc_raw = exp(clip(conserved_source));
// psum partials for softmax denominator.
// ---------------------------------------------------------------------------
__global__ __launch_bounds__(256) void stage2_part_kernel(
    const float* __restrict__ q, const float* __restrict__ k,
    const float* __restrict__ qsi, const float* __restrict__ kso,
    float* __restrict__ sa, float* __restrict__ sc, float* __restrict__ psum_p)
{
    const int nh = blockIdx.x, ch = blockIdx.y;
    const float* qp = q + (size_t)nh * L_ * HD_;
    const float* kp = k + (size_t)nh * L_ * HD_;
    const int lane = threadIdx.x & 63;
    const int w = threadIdx.x >> 6;
    const float ksov = kso[nh * 64 + lane] + EPS_;
    const float qsiv = qsi[nh * 64 + lane] + EPS_;
    float psum = 0.f;
    for (int l = ch * 128 + w; l < (ch + 1) * 128; l += 4) {
        float a = (qp[(size_t)l * HD_ + lane] + EPS_) * ksov;
        float b = (kp[(size_t)l * HD_ + lane] + EPS_) * qsiv;
        #pragma unroll
        for (int off = 32; off >= 1; off >>= 1) {
            a += __shfl_xor(a, off, 64);
            b += __shfl_xor(b, off, 64);
        }
        b = fminf(1.f, fmaxf(-1.f, b));
        const float p = expf(b);
        if (lane == 0) {
            sa[nh * L_ + l] = sigmoidf_(a);
            sc[nh * L_ + l] = p;
        }
        psum += p;    // same on all lanes of wave
    }
    __shared__ float sp[4];
    if (lane == 0) sp[w] = psum;
    __syncthreads();
    if (threadIdx.x == 0) psum_p[nh * 16 + ch] = sp[0] + sp[1] + sp[2] + sp[3];
}

// ---------------------------------------------------------------------------
// kv partial over 256-l chunk: kvp[nh][ch][d][m] = sum k[l][d]*v[l][m]*sc[l]*scale
// ---------------------------------------------------------------------------
__global__ __launch_bounds__(256) void kv_part_kernel(
    const float* __restrict__ k, const float* __restrict__ v,
    const float* __restrict__ sc, const float* __restrict__ psum_p,
    float* __restrict__ kvp)
{
    const int nh = blockIdx.x, ch = blockIdx.y;
    const float* kp = k + (size_t)nh * L_ * HD_;
    const float* vp = v + (size_t)nh * L_ * HD_;
    const float* scp = sc + (size_t)nh * L_;
    float tot = 0.f;
    #pragma unroll
    for (int i = 0; i < 16; ++i) tot += psum_p[nh * 16 + i];
    const float scale = (float)L_ / tot;

    const int m  = threadIdx.x & 63;
    const int dg = threadIdx.x >> 6;
    float acc[16] = {0.f};
    __shared__ float ks[32][64], vs[32][64];
    for (int l0 = ch * 256; l0 < (ch + 1) * 256; l0 += 32) {
        for (int i = threadIdx.x; i < 32 * 64; i += 256) {
            const int ll = i >> 6, dd = i & 63;
            ks[ll][dd] = kp[(size_t)(l0 + ll) * HD_ + dd];
            vs[ll][dd] = vp[(size_t)(l0 + ll) * HD_ + dd] * (scp[l0 + ll] * scale);
        }
        __syncthreads();
        #pragma unroll 8
        for (int ll = 0; ll < 32; ++ll) {
            const float vv = vs[ll][m];
            #pragma unroll
            for (int dd = 0; dd < 16; ++dd) acc[dd] += ks[ll][dg * 16 + dd] * vv;
        }
        __syncthreads();
    }
    #pragma unroll
    for (int dd = 0; dd < 16; ++dd)
        kvp[((size_t)(nh * 8 + ch) * 64 + (dg * 16 + dd)) * 64 + m] = acc[dd];
}

__global__ __launch_bounds__(256) void kv_reduce_kernel(
    const float* __restrict__ kvp, float* __restrict__ kvb)
{
    const int nh = blockIdx.x;
    for (int e = threadIdx.x; e < 4096; e += 256) {
        float s = 0.f;
        #pragma unroll
        for (int c = 0; c < 8; ++c) s += kvp[(size_t)(nh * 8 + c) * 4096 + e];
        kvb[(size_t)nh * 4096 + e] = s;
    }
}

// ---------------------------------------------------------------------------
// out: attn[n][l][h*64+m] = sa*si*(q[l,:]·kv[:,m]) -> bf16 hi/lo split store
// ---------------------------------------------------------------------------
__global__ __launch_bounds__(256) void out_kernel(
    const float* __restrict__ q, const float* __restrict__ kvb,
    const float* __restrict__ si, const float* __restrict__ sa,
    short* __restrict__ attn_h, short* __restrict__ attn_l)
{
    const int nh = blockIdx.x;
    const int n = nh >> 4;
    const int h = nh & 15;
    const int l0 = blockIdx.y * 64;
    __shared__ float kvs[64][64];
    __shared__ float qs[64][64];
    for (int i = threadIdx.x; i < 4096; i += 256)
        kvs[i >> 6][i & 63] = kvb[(size_t)nh * 4096 + i];
    for (int i = threadIdx.x; i < 4096; i += 256) {
        const int ll = i >> 6, dd = i & 63;
        qs[ll][dd] = q[((size_t)nh * L_ + (l0 + ll)) * HD_ + dd];
    }
    __syncthreads();
    const int m = threadIdx.x & 63;
    const int lg = threadIdx.x >> 6;
    for (int ll = lg; ll < 64; ll += 4) {
        const int l = l0 + ll;
        float acc = 0.f;
        #pragma unroll
        for (int d = 0; d < 64; ++d) acc += qs[ll][d] * kvs[d][m];
        const float val = acc * si[nh * L_ + l] * sa[nh * L_ + l];
        const size_t idx = ((size_t)n * L_ + l) * DM + h * 64 + m;
        const short hb = f2bf(val);
        attn_h[idx] = hb;
        attn_l[idx] = f2bf(val - bf2f(hb));
    }
}

extern "C" void kernel_launch(void* const* d_in, const int* in_sizes, int n_in,
                              void* d_out, int out_size, void* d_ws, size_t ws_size,
                              hipStream_t stream)
{
    const float* x  = (const float*)d_in[0];
    const float* Wq = (const float*)d_in[1];
    const float* bq = (const float*)d_in[2];
    const float* Wk = (const float*)d_in[3];
    const float* bk = (const float*)d_in[4];
    const float* Wv = (const float*)d_in[5];
    const float* bv = (const float*)d_in[6];
    const float* Wo = (const float*)d_in[7];
    const float* bo = (const float*)d_in[8];
    float* out = (float*)d_out;

    float* ws = (float*)d_ws;
    size_t off = 0;
    const size_t big = (size_t)B_ * L_ * DM;   // 8,388,608 elems
    float* qbuf = ws + off; off += big;
    float* kbuf = ws + off; off += big;
    float* vbuf = ws + off; off += big;
    // union region: x hi/lo during projections, attn hi/lo afterwards
    short* xh = (short*)(ws + off);
    short* xl = xh + big;
    short* attn_h = xh;
    short* attn_l = xl;
    off += big;
    short* wh3 = (short*)(ws + off); off += (size_t)3 * DM * DM / 2;
    short* wl3 = (short*)(ws + off); off += (size_t)3 * DM * DM / 2;
    short* woh = (short*)(ws + off); off += (size_t)DM * DM / 2;
    short* wol = (short*)(ws + off); off += (size_t)DM * DM / 2;
    float* kvp    = ws + off; off += (size_t)NH_ * 8 * 64 * 64;
    float* kvb    = ws + off; off += (size_t)NH_ * 64 * 64;
    float* qsum_p = ws + off; off += NH_ * 16 * 64;
    float* ksum_p = ws + off; off += NH_ * 16 * 64;
    float* qsi_p  = ws + off; off += NH_ * 16 * 64;
    float* kso_p  = ws + off; off += NH_ * 16 * 64;
    float* psum_p = ws + off; off += NH_ * 16;
    float* qsum   = ws + off; off += NH_ * 64;
    float* ksum   = ws + off; off += NH_ * 64;
    float* qsi    = ws + off; off += NH_ * 64;
    float* kso    = ws + off; off += NH_ * 64;
    float* si     = ws + off; off += NH_ * L_;
    float* sa     = ws + off; off += NH_ * L_;
    float* sc     = ws + off; off += NH_ * L_;

    // 1. split inputs to bf16 hi/lo
    split_kernel<<<big / 4 / 256, 256, 0, stream>>>(x, xh, xl, (int)(big / 4));
    const int wblk = DM * DM / 4 / 256;   // 1024
    split_kernel<<<wblk, 256, 0, stream>>>(Wq, wh3,               wl3,               DM * DM / 4);
    split_kernel<<<wblk, 256, 0, stream>>>(Wk, wh3 + DM * DM,     wl3 + DM * DM,     DM * DM / 4);
    split_kernel<<<wblk, 256, 0, stream>>>(Wv, wh3 + 2 * DM * DM, wl3 + 2 * DM * DM, DM * DM / 4);
    split_kernel<<<wblk, 256, 0, stream>>>(Wo, woh,               wol,               DM * DM / 4);

    // 2. QKV projection GEMM (packed N'=3072; grid 768 = 3.0 rounds balanced)
    gemm_qkv_kernel<<<768, 512, 0, stream>>>(xh, xl, wh3, wl3, bq, bk, bv, qbuf, kbuf, vbuf);

    // 3. flow-conservation normalizations
    dim3 g16(NH_, 16);
    colsum_part_kernel<<<g16, 256, 0, stream>>>(qbuf, kbuf, qsum_p, ksum_p);
    reduce16_2_kernel<<<NH_, 64, 0, stream>>>(qsum_p, ksum_p, qsum, ksum);
    stage1_part_kernel<<<g16, 256, 0, stream>>>(qbuf, kbuf, qsum, ksum, si, qsi_p, kso_p);
    reduce16_2_kernel<<<NH_, 64, 0, stream>>>(qsi_p, kso_p, qsi, kso);
    stage2_part_kernel<<<g16, 256, 0, stream>>>(qbuf, kbuf, qsi, kso, sa, sc, psum_p);

    // 4. linear-attention kv + out
    kv_part_kernel<<<dim3(NH_, 8), 256, 0, stream>>>(kbuf, vbuf, sc, psum_p, kvp);
    kv_reduce_kernel<<<NH_, 256, 0, stream>>>(kvp, kvb);
    out_kernel<<<dim3(NH_, L_ / 64), 256, 0, stream>>>(qbuf, kvb, si, sa, attn_h, attn_l);

    // 5. output projection GEMM (grid 256 = 1.0 rounds exact)
    gemm_out_kernel<<<256, 512, 0, stream>>>(attn_h, attn_l, woh, wol, bo, out);
}

// Round 7
// 415.034 us; speedup vs baseline: 1.0493x; 1.0083x over previous
//
#include <hip/hip_runtime.h>
#include <math.h>

#define B_ 4
#define L_ 2048
#define DM 1024
#define H_ 16
#define HD_ 64
#define NH_ 64            // B_*H_
#define EPS_ 1e-6f

typedef float f32x4 __attribute__((ext_vector_type(4)));
typedef short short8 __attribute__((ext_vector_type(8)));

typedef __attribute__((address_space(3))) void lds_v;
typedef const __attribute__((address_space(1))) void glb_v;
#define GLOAD16(g, l) __builtin_amdgcn_global_load_lds((glb_v*)(g), (lds_v*)(l), 16, 0, 0)

__device__ __forceinline__ float sigmoidf_(float x) { return 1.0f / (1.0f + expf(-x)); }

// round-to-nearest-even f32 -> bf16 bits
__device__ __forceinline__ short f2bf(float x) {
    unsigned u = __float_as_uint(x);
    unsigned r = (u + 0x7FFFu + ((u >> 16) & 1u)) >> 16;
    return (short)r;
}
__device__ __forceinline__ float bf2f(short h) {
    return __uint_as_float(((unsigned)(unsigned short)h) << 16);
}

__global__ __launch_bounds__(256) void zero_kernel(float* __restrict__ p, int n)
{
    const int i = blockIdx.x * 256 + threadIdx.x;
    if (i < n) p[i] = 0.f;
}

// ---------------------------------------------------------------------------
// Split f32 array into bf16 hi/lo (x = hi + lo to ~2^-17 relative).
// ---------------------------------------------------------------------------
__global__ __launch_bounds__(256) void split_kernel(
    const float* __restrict__ in, short* __restrict__ hi, short* __restrict__ lo, int n4)
{
    const int i = blockIdx.x * 256 + threadIdx.x;
    if (i >= n4) return;
    f32x4 v = *(const f32x4*)(in + (size_t)i * 4);
    short h[4], l[4];
    #pragma unroll
    for (int j = 0; j < 4; ++j) {
        h[j] = f2bf(v[j]);
        l[j] = f2bf(v[j] - bf2f(h[j]));
    }
    typedef short short4_ __attribute__((ext_vector_type(4)));
    *(short4_*)(hi + (size_t)i * 4) = short4_{h[0], h[1], h[2], h[3]};
    *(short4_*)(lo + (size_t)i * 4) = short4_{l[0], l[1], l[2], l[3]};
}

// all 4 weight splits in one launch (blockIdx.y selects the matrix)
__global__ __launch_bounds__(256) void split_w4_kernel(
    const float* __restrict__ Wq, const float* __restrict__ Wk,
    const float* __restrict__ Wv, const float* __restrict__ Wo,
    short* __restrict__ wh3, short* __restrict__ wl3,
    short* __restrict__ woh, short* __restrict__ wol)
{
    const int y = blockIdx.y;
    const float* src = (y == 0) ? Wq : (y == 1) ? Wk : (y == 2) ? Wv : Wo;
    short* hh = (y < 3) ? (wh3 + (size_t)y * DM * DM) : woh;
    short* ll = (y < 3) ? (wl3 + (size_t)y * DM * DM) : wol;
    const int i = blockIdx.x * 256 + threadIdx.x;   // i < DM*DM/4
    f32x4 v = *(const f32x4*)(src + (size_t)i * 4);
    short h[4], l[4];
    #pragma unroll
    for (int j = 0; j < 4; ++j) {
        h[j] = f2bf(v[j]);
        l[j] = f2bf(v[j] - bf2f(h[j]));
    }
    typedef short short4_ __attribute__((ext_vector_type(4)));
    *(short4_*)(hh + (size_t)i * 4) = short4_{h[0], h[1], h[2], h[3]};
    *(short4_*)(ll + (size_t)i * 4) = short4_{l[0], l[1], l[2], l[3]};
}

// ---------------------------------------------------------------------------
// MFMA GEMM core (proven R2 m97-structure): C[128x128] tile of
// A[M,1024] @ W[N,1024]^T, split-bf16 3-product.  LDS [128][32] bf16 tiles,
// 16B-slot swizzle (2-way, free); linear gload_lds dest + inverse-swizzled
// source + swizzled ds_read.
// ---------------------------------------------------------------------------
__device__ __forceinline__ void gemm_core(
    const short* __restrict__ Ah_g, const short* __restrict__ Al_g,
    const short* __restrict__ Bh_g, const short* __restrict__ Bl_g,
    int row0, int col0, short* lds, f32x4 acc[4][4])
{
    const int t = threadIdx.x;
    const int lane = t & 63;
    const int w = t >> 6;
    const int wr = w >> 1, wc = w & 1;
    const int fr = lane & 15, kc = lane >> 4;

    for (int k0 = 0; k0 < DM; k0 += 32) {
        const short* a_h = Ah_g + (size_t)row0 * DM + k0;
        const short* a_l = Al_g + (size_t)row0 * DM + k0;
        const short* b_h = Bh_g + (size_t)col0 * DM + k0;
        const short* b_l = Bl_g + (size_t)col0 * DM + k0;
        #pragma unroll
        for (int p = 0; p < 2; ++p) {
            const int b = p * 4096 + t * 16;          // linear byte in 8 KB tile
            const int r = b >> 6;                     // row 0..127
            const int s = (b >> 4) & 3;               // 16B slot in row
            const int fsw = (r & 3) ^ ((r >> 2) & 3);
            const int c = ((s ^ fsw) << 3);           // inverse-swizzled k-elem
            const size_t go = (size_t)r * DM + c;
            GLOAD16(a_h + go, lds + 0 * 4096 + (b >> 1));
            GLOAD16(a_l + go, lds + 1 * 4096 + (b >> 1));
            GLOAD16(b_h + go, lds + 2 * 4096 + (b >> 1));
            GLOAD16(b_l + go, lds + 3 * 4096 + (b >> 1));
        }
        __syncthreads();

        short8 bhf[4], blf[4];
        #pragma unroll
        for (int n = 0; n < 4; ++n) {
            const int row = wc * 64 + n * 16 + fr;
            const int fsw = (row & 3) ^ ((row >> 2) & 3);
            const int off = row * 32 + ((kc ^ fsw) << 3);
            bhf[n] = *(const short8*)(lds + 2 * 4096 + off);
            blf[n] = *(const short8*)(lds + 3 * 4096 + off);
        }
        #pragma unroll
        for (int m = 0; m < 4; ++m) {
            const int row = wr * 64 + m * 16 + fr;
            const int fsw = (row & 3) ^ ((row >> 2) & 3);
            const int off = row * 32 + ((kc ^ fsw) << 3);
            short8 ahf = *(const short8*)(lds + 0 * 4096 + off);
            short8 alf = *(const short8*)(lds + 1 * 4096 + off);
            #pragma unroll
            for (int n = 0; n < 4; ++n) {
                acc[m][n] = __builtin_amdgcn_mfma_f32_16x16x32_bf16(ahf, bhf[n], acc[m][n], 0, 0, 0);
                acc[m][n] = __builtin_amdgcn_mfma_f32_16x16x32_bf16(ahf, blf[n], acc[m][n], 0, 0, 0);
                acc[m][n] = __builtin_amdgcn_mfma_f32_16x16x32_bf16(alf, bhf[n], acc[m][n], 0, 0, 0);
            }
        }
        __syncthreads();
    }
}

// QKV GEMM: z selects q/k/v.  Epilogue: +bias, sigmoid for q,k, scatter to
// [B,H,L,HD] f32, and FUSED column-sum (post-sigmoid) -> atomicAdd qsum/ksum.
__global__ __launch_bounds__(256) void gemm_qkv_kernel(
    const short* __restrict__ xh, const short* __restrict__ xl,
    const short* __restrict__ wh, const short* __restrict__ wl,   // packed 3x [DM][DM]
    const float* __restrict__ bq, const float* __restrict__ bk, const float* __restrict__ bv,
    float* __restrict__ qb, float* __restrict__ kb, float* __restrict__ vb,
    float* __restrict__ qsum, float* __restrict__ ksum)
{
    const int z = blockIdx.z;
    const float* __restrict__ bias = (z == 0) ? bq : (z == 1) ? bk : bv;
    float* __restrict__ outp       = (z == 0) ? qb : (z == 1) ? kb : vb;
    const short* Wh = wh + (size_t)z * DM * DM;
    const short* Wl = wl + (size_t)z * DM * DM;

    __shared__ short lds[4 * 4096];
    const int row0 = blockIdx.y * 128;
    const int col0 = blockIdx.x * 128;
    f32x4 acc[4][4];
    #pragma unroll
    for (int m = 0; m < 4; ++m)
        #pragma unroll
        for (int n = 0; n < 4; ++n) acc[m][n] = f32x4{0.f, 0.f, 0.f, 0.f};

    gemm_core(xh, xl, Wh, Wl, row0, col0, lds, acc);

    const int tid = threadIdx.x;
    const int lane = tid & 63;
    const int w = tid >> 6;
    const int wr = w >> 1, wc = w & 1;
    const int fr = lane & 15, kc = lane >> 4;
    float csum[4] = {0.f, 0.f, 0.f, 0.f};
    #pragma unroll
    for (int m = 0; m < 4; ++m) {
        const int gr0 = row0 + wr * 64 + m * 16 + kc * 4;
        #pragma unroll
        for (int n = 0; n < 4; ++n) {
            const int j = col0 + wc * 64 + n * 16 + fr;
            const float bj = bias[j];
            const int h = j >> 6, dd = j & 63;
            #pragma unroll
            for (int r2 = 0; r2 < 4; ++r2) {
                const int i = gr0 + r2;
                const int nn = i >> 11, l = i & (L_ - 1);
                float v = acc[m][n][r2] + bj;
                if (z < 2) { v = sigmoidf_(v); csum[n] += v; }
                outp[(((size_t)(nn * H_ + h)) * L_ + l) * HD_ + dd] = v;
            }
        }
    }

    // fused colsum: 128 tile rows (one nn) x 128 tile cols -> qsum/ksum
    if (z < 2) {
        float* scol = (float*)lds;             // reuse LDS (gemm_core ended with barrier)
        if (tid < 128) scol[tid] = 0.f;
        __syncthreads();
        #pragma unroll
        for (int n = 0; n < 4; ++n)
            atomicAdd(&scol[wc * 64 + n * 16 + fr], csum[n]);
        __syncthreads();
        if (tid < 128) {
            const int j = col0 + tid;
            const int nn = row0 >> 11;
            float* dst = (z == 0) ? qsum : ksum;
            atomicAdd(&dst[(nn * H_ + (j >> 6)) * 64 + (j & 63)], scol[tid]);
        }
    }
}

// Final GEMM: out = attn_hi/lo @ Wo^T + bo, plain [B*L, DM] f32 store.
__global__ __launch_bounds__(256) void gemm_out_kernel(
    const short* __restrict__ ah, const short* __restrict__ al,
    const short* __restrict__ wh, const short* __restrict__ wl,
    const float* __restrict__ bias, float* __restrict__ outp)
{
    __shared__ short lds[4 * 4096];
    const int row0 = blockIdx.y * 128;
    const int col0 = blockIdx.x * 128;
    f32x4 acc[4][4];
    #pragma unroll
    for (int m = 0; m < 4; ++m)
        #pragma unroll
        for (int n = 0; n < 4; ++n) acc[m][n] = f32x4{0.f, 0.f, 0.f, 0.f};

    gemm_core(ah, al, wh, wl, row0, col0, lds, acc);

    const int lane = threadIdx.x & 63;
    const int w = threadIdx.x >> 6;
    const int wr = w >> 1, wc = w & 1;
    const int fr = lane & 15, kc = lane >> 4;
    #pragma unroll
    for (int m = 0; m < 4; ++m) {
        const int gr0 = row0 + wr * 64 + m * 16 + kc * 4;
        #pragma unroll
        for (int n = 0; n < 4; ++n) {
            const int j = col0 + wc * 64 + n * 16 + fr;
            const float bj = bias[j];
            #pragma unroll
            for (int r2 = 0; r2 < 4; ++r2)
                outp[(size_t)(gr0 + r2) * DM + j] = acc[m][n][r2] + bj;
        }
    }
}

// ---------------------------------------------------------------------------
// stage1: per l compute si (stored) and so (inline); atomicAdd qsi/kso.
// ---------------------------------------------------------------------------
__global__ __launch_bounds__(256) void stage1_part_kernel(
    const float* __restrict__ q, const float* __restrict__ k,
    const float* __restrict__ qsum, const float* __restrict__ ksum,
    float* __restrict__ si, float* __restrict__ qsi, float* __restrict__ kso)
{
    const int nh = blockIdx.x, ch = blockIdx.y;
    const float* qp = q + (size_t)nh * L_ * HD_;
    const float* kp = k + (size_t)nh * L_ * HD_;
    const int lane = threadIdx.x & 63;
    const int w = threadIdx.x >> 6;
    const float ksv = ksum[nh * 64 + lane] + EPS_;
    const float qsv = qsum[nh * 64 + lane] + EPS_;
    float qsi_acc = 0.f, kso_acc = 0.f;
    for (int l = ch * 128 + w; l < (ch + 1) * 128; l += 4) {
        const float qv = qp[(size_t)l * HD_ + lane];
        const float kv = kp[(size_t)l * HD_ + lane];
        float a = (qv + EPS_) * ksv;
        float b = (kv + EPS_) * qsv;
        #pragma unroll
        for (int off = 32; off >= 1; off >>= 1) {
            a += __shfl_xor(a, off, 64);
            b += __shfl_xor(b, off, 64);
        }
        const float siv = 1.f / a;
        const float sov = 1.f / b;
        if (lane == 0) si[nh * L_ + l] = siv;
        qsi_acc += qv * siv;
        kso_acc += kv * sov;
    }
    __shared__ float s1[4][64], s2[4][64];
    s1[w][lane] = qsi_acc; s2[w][lane] = kso_acc;
    __syncthreads();
    if (w == 0) {
        atomicAdd(&qsi[nh * 64 + lane], s1[0][lane] + s1[1][lane] + s1[2][lane] + s1[3][lane]);
        atomicAdd(&kso[nh * 64 + lane], s2[0][lane] + s2[1][lane] + s2[2][lane] + s2[3][lane]);
    }
}

// ---------------------------------------------------------------------------
// kv partial over 256-l chunk WITH fused source-competition numerator:
//   p[l] = exp(clip((k[l]+eps)·(qsi+eps), -1, 1))     (softmax numerator)
//   kvp[nh][ch][d][m] = sum_l k[l][d] * v[l][m] * p[l]   (raw, scale deferred)
//   psum_p[nh][ch] = sum_l p[l]
// ---------------------------------------------------------------------------
__global__ __launch_bounds__(256) void kv_part_kernel(
    const float* __restrict__ k, const float* __restrict__ v,
    const float* __restrict__ qsi, float* __restrict__ kvp, float* __restrict__ psum_p)
{
    const int nh = blockIdx.x, ch = blockIdx.y;
    const float* kp = k + (size_t)nh * L_ * HD_;
    const float* vp = v + (size_t)nh * L_ * HD_;
    const int lane = threadIdx.x & 63;
    const int w = threadIdx.x >> 6;
    const float qsiv = qsi[nh * 64 + lane] + EPS_;

    float acc[16] = {0.f};
    float psum = 0.f;
    __shared__ float ks[32][64], vs[32][64];
    __shared__ float pl[32];
    for (int l0 = ch * 256; l0 < (ch + 1) * 256; l0 += 32) {
        for (int i = threadIdx.x; i < 32 * 64; i += 256) {
            const int ll = i >> 6, dd = i & 63;
            ks[ll][dd] = kp[(size_t)(l0 + ll) * HD_ + dd];
            vs[ll][dd] = vp[(size_t)(l0 + ll) * HD_ + dd];
        }
        __syncthreads();
        // p for this tile's 32 rows; wave w owns rows w*8..w*8+7
        #pragma unroll
        for (int ll = w * 8; ll < w * 8 + 8; ++ll) {
            float b = (ks[ll][lane] + EPS_) * qsiv;
            #pragma unroll
            for (int off = 32; off >= 1; off >>= 1) b += __shfl_xor(b, off, 64);
            b = fminf(1.f, fmaxf(-1.f, b));
            const float p = expf(b);
            if (lane == 0) pl[ll] = p;
            psum += p;            // identical on all lanes; lane0 harvested later
        }
        __syncthreads();
        #pragma unroll 4
        for (int ll = 0; ll < 32; ++ll) {
            const float vv = vs[ll][lane] * pl[ll];
            #pragma unroll
            for (int dd = 0; dd < 16; ++dd) acc[dd] += ks[ll][w * 16 + dd] * vv;
        }
        __syncthreads();
    }
    #pragma unroll
    for (int dd = 0; dd < 16; ++dd)
        kvp[((size_t)(nh * 8 + ch) * 64 + (w * 16 + dd)) * 64 + lane] = acc[dd];

    __shared__ float sp[4];
    if (lane == 0) sp[w] = psum;
    __syncthreads();
    if (threadIdx.x == 0) psum_p[nh * 8 + ch] = sp[0] + sp[1] + sp[2] + sp[3];
}

// reduce kv partials and apply deferred softmax scale L/tot
__global__ __launch_bounds__(256) void kv_reduce_kernel(
    const float* __restrict__ kvp, const float* __restrict__ psum_p,
    float* __restrict__ kvb)
{
    const int nh = blockIdx.x;
    float tot = 0.f;
    #pragma unroll
    for (int c = 0; c < 8; ++c) tot += psum_p[nh * 8 + c];
    const float scale = (float)L_ / tot;
    for (int e = threadIdx.x; e < 4096; e += 256) {
        float s = 0.f;
        #pragma unroll
        for (int c = 0; c < 8; ++c) s += kvp[(size_t)(nh * 8 + c) * 4096 + e];
        kvb[(size_t)nh * 4096 + e] = s * scale;
    }
}

// ---------------------------------------------------------------------------
// out with fused sink_allocation:
//   sa[l] = sigmoid((q[l]+eps)·(kso+eps))   computed from the staged q tile
//   attn[n][l][h*64+m] = sa[l]*si[l]*(q[l,:]·kv[:,m]) -> bf16 hi/lo store
// ---------------------------------------------------------------------------
__global__ __launch_bounds__(256) void out_kernel(
    const float* __restrict__ q, const float* __restrict__ kvb,
    const float* __restrict__ si, const float* __restrict__ kso,
    short* __restrict__ attn_h, short* __restrict__ attn_l)
{
    const int nh = blockIdx.x;
    const int n = nh >> 4;
    const int h = nh & 15;
    const int l0 = blockIdx.y * 64;
    __shared__ float kvs[64][64];
    __shared__ float qs[64][64];
    __shared__ float sal[64];
    for (int i = threadIdx.x; i < 4096; i += 256)
        kvs[i >> 6][i & 63] = kvb[(size_t)nh * 4096 + i];
    for (int i = threadIdx.x; i < 4096; i += 256) {
        const int ll = i >> 6, dd = i & 63;
        qs[ll][dd] = q[((size_t)nh * L_ + (l0 + ll)) * HD_ + dd];
    }
    __syncthreads();
    const int lane = threadIdx.x & 63;
    const int w = threadIdx.x >> 6;
    const float ksov = kso[nh * 64 + lane] + EPS_;
    for (int ll = w; ll < 64; ll += 4) {
        float a = (qs[ll][lane] + EPS_) * ksov;
        #pragma unroll
        for (int off = 32; off >= 1; off >>= 1) a += __shfl_xor(a, off, 64);
        if (lane == 0) sal[ll] = sigmoidf_(a);
    }
    __syncthreads();
    for (int ll = w; ll < 64; ll += 4) {
        const int l = l0 + ll;
        float acc = 0.f;
        #pragma unroll
        for (int d = 0; d < 64; ++d) acc += qs[ll][d] * kvs[d][lane];
        const float val = acc * si[nh * L_ + l] * sal[ll];
        const size_t idx = ((size_t)n * L_ + l) * DM + h * 64 + lane;
        const short hb = f2bf(val);
        attn_h[idx] = hb;
        attn_l[idx] = f2bf(val - bf2f(hb));
    }
}

extern "C" void kernel_launch(void* const* d_in, const int* in_sizes, int n_in,
                              void* d_out, int out_size, void* d_ws, size_t ws_size,
                              hipStream_t stream)
{
    const float* x  = (const float*)d_in[0];
    const float* Wq = (const float*)d_in[1];
    const float* bq = (const float*)d_in[2];
    const float* Wk = (const float*)d_in[3];
    const float* bk = (const float*)d_in[4];
    const float* Wv = (const float*)d_in[5];
    const float* bv = (const float*)d_in[6];
    const float* Wo = (const float*)d_in[7];
    const float* bo = (const float*)d_in[8];
    float* out = (float*)d_out;

    float* ws = (float*)d_ws;
    size_t off = 0;
    const size_t big = (size_t)B_ * L_ * DM;   // 8,388,608 elems
    float* qbuf = ws + off; off += big;
    float* kbuf = ws + off; off += big;
    float* vbuf = ws + off; off += big;
    // union region: x hi/lo during projections, attn hi/lo afterwards
    short* xh = (short*)(ws + off);
    short* xl = xh + big;
    short* attn_h = xh;
    short* attn_l = xl;
    off += big;
    short* wh3 = (short*)(ws + off); off += (size_t)3 * DM * DM / 2;
    short* wl3 = (short*)(ws + off); off += (size_t)3 * DM * DM / 2;
    short* woh = (short*)(ws + off); off += (size_t)DM * DM / 2;
    short* wol = (short*)(ws + off); off += (size_t)DM * DM / 2;
    float* kvp    = ws + off; off += (size_t)NH_ * 8 * 64 * 64;
    float* kvb    = ws + off; off += (size_t)NH_ * 64 * 64;
    // zero-initialized accumulator block (contiguous): qsum|ksum|qsi|kso
    float* sums = ws + off;
    float* qsum = sums;
    float* ksum = sums + 1 * NH_ * 64;
    float* qsi  = sums + 2 * NH_ * 64;
    float* kso  = sums + 3 * NH_ * 64;
    off += 4 * NH_ * 64;
    float* psum_p = ws + off; off += NH_ * 8;
    float* si     = ws + off; off += NH_ * L_;

    // 0. zero the atomic accumulators (16384 floats)
    zero_kernel<<<(4 * NH_ * 64 + 255) / 256, 256, 0, stream>>>(sums, 4 * NH_ * 64);

    // 1. split inputs to bf16 hi/lo
    split_kernel<<<big / 4 / 256, 256, 0, stream>>>(x, xh, xl, (int)(big / 4));
    split_w4_kernel<<<dim3(DM * DM / 4 / 256, 4), 256, 0, stream>>>(
        Wq, Wk, Wv, Wo, wh3, wl3, woh, wol);

    // 2. QKV projection GEMMs (MFMA) + fused colsum
    dim3 gqkv(DM / 128, (B_ * L_) / 128, 3);
    gemm_qkv_kernel<<<gqkv, 256, 0, stream>>>(xh, xl, wh3, wl3, bq, bk, bv,
                                              qbuf, kbuf, vbuf, qsum, ksum);

    // 3. stage1 (si + qsi/kso atomics)
    stage1_part_kernel<<<dim3(NH_, 16), 256, 0, stream>>>(qbuf, kbuf, qsum, ksum, si, qsi, kso);

    // 4. kv with fused source-competition; deferred softmax scale in reduce
    kv_part_kernel<<<dim3(NH_, 8), 256, 0, stream>>>(kbuf, vbuf, qsi, kvp, psum_p);
    kv_reduce_kernel<<<NH_, 256, 0, stream>>>(kvp, psum_p, kvb);

    // 5. out with fused sink_allocation -> bf16 hi/lo attn
    out_kernel<<<dim3(NH_, L_ / 64), 256, 0, stream>>>(qbuf, kvb, si, kso, attn_h, attn_l);

    // 6. output projection GEMM
    dim3 gout(DM / 128, (B_ * L_) / 128);
    gemm_out_kernel<<<gout, 256, 0, stream>>>(attn_h, attn_l, woh, wol, bo, out);
}